// Round 1
// baseline (1222.968 us; speedup 1.0000x reference)
//
#include <hip/hip_runtime.h>
#include <hip/hip_bf16.h>
#include <math.h>

#define HD 1024
#define BD 32
#define TD 64
#define VD 32000

typedef __attribute__((ext_vector_type(8))) short bf16x8;
typedef __attribute__((ext_vector_type(4))) float f32x4;

__device__ __forceinline__ short f2bf(float x) {
    __hip_bfloat16 h = __float2bfloat16(x);
    union { __hip_bfloat16 h; short s; } u; u.h = h; return u.s;
}

// ---------------- init: casts + bias fold + state init ----------------
__global__ __launch_bounds__(256) void init_kernel(
    const float* __restrict__ Whh_f, const float* __restrict__ bih,
    const float* __restrict__ bhh,  const float* __restrict__ Wout_f,
    const float* __restrict__ h0,   const float* __restrict__ c0,
    short* __restrict__ Whh_b, short* __restrict__ Wout_b,
    float* __restrict__ bias,  short* __restrict__ h_st, float* __restrict__ c_st)
{
    long i0 = (long)blockIdx.x * blockDim.x + threadIdx.x;
    long stride = (long)gridDim.x * blockDim.x;
    for (long i = i0; i < (long)VD * HD / 4; i += stride) {
        float4 x = ((const float4*)Wout_f)[i];
        short4 y; y.x = f2bf(x.x); y.y = f2bf(x.y); y.z = f2bf(x.z); y.w = f2bf(x.w);
        ((short4*)Wout_b)[i] = y;
    }
    for (long i = i0; i < (long)4 * HD * HD / 4; i += stride) {
        float4 x = ((const float4*)Whh_f)[i];
        short4 y; y.x = f2bf(x.x); y.y = f2bf(x.y); y.z = f2bf(x.z); y.w = f2bf(x.w);
        ((short4*)Whh_b)[i] = y;
    }
    for (long i = i0; i < 4 * HD; i += stride) bias[i] = bih[i] + bhh[i];
    for (long i = i0; i < BD * HD; i += stride) {
        h_st[i] = f2bf(h0[i]);   // ping buffer 0
        c_st[i] = c0[i];
    }
}

// ---------------- one LSTM step: 128 WGs x 1 wave, MFMA gates ----------------
// WG w owns hidden indices j in [w*8, w*8+8) and all 4 gates for them.
__global__ __launch_bounds__(64) void lstm_step(
    const short* __restrict__ Whh_b,   // [4096][1024] bf16
    const float* __restrict__ bias,    // [4096] = b_ih + b_hh
    const short* __restrict__ hin,     // [32][1024] bf16
    short* __restrict__ hout,          // [32][1024] bf16
    float* __restrict__ c_st,          // [32][1024] f32
    short* __restrict__ Hmat,          // [32][64][1024] bf16
    int t)
{
    const int w = blockIdx.x;       // 0..127
    const int l = threadIdx.x;      // 0..63
    const int lo = l & 15, hi = l >> 4;
    const int j0 = w * 8;

    // B columns: n_local = g*8 + jl  ->  W_hh row = g*1024 + j0 + jl
    int brow[2];
    #pragma unroll
    for (int nf = 0; nf < 2; nf++) {
        int n = nf * 16 + lo;
        brow[nf] = (n >> 3) * HD + j0 + (n & 7);
    }
    const short* hA0 = hin + lo * HD;
    const short* hA1 = hin + (16 + lo) * HD;
    const short* wB0 = Whh_b + (long)brow[0] * HD;
    const short* wB1 = Whh_b + (long)brow[1] * HD;

    f32x4 acc[2][2] = {};
    for (int ks = 0; ks < 32; ks++) {
        int k = ks * 32 + hi * 8;
        bf16x8 a0 = *(const bf16x8*)(hA0 + k);
        bf16x8 a1 = *(const bf16x8*)(hA1 + k);
        bf16x8 b0 = *(const bf16x8*)(wB0 + k);
        bf16x8 b1 = *(const bf16x8*)(wB1 + k);
        acc[0][0] = __builtin_amdgcn_mfma_f32_16x16x32_bf16(a0, b0, acc[0][0], 0, 0, 0);
        acc[1][0] = __builtin_amdgcn_mfma_f32_16x16x32_bf16(a1, b0, acc[1][0], 0, 0, 0);
        acc[0][1] = __builtin_amdgcn_mfma_f32_16x16x32_bf16(a0, b1, acc[0][1], 0, 0, 0);
        acc[1][1] = __builtin_amdgcn_mfma_f32_16x16x32_bf16(a1, b1, acc[1][1], 0, 0, 0);
    }

    __shared__ float gl[BD][33];
    #pragma unroll
    for (int mf = 0; mf < 2; mf++)
        #pragma unroll
        for (int nf = 0; nf < 2; nf++)
            #pragma unroll
            for (int r = 0; r < 4; r++)
                gl[mf * 16 + hi * 4 + r][nf * 16 + lo] = acc[mf][nf][r];
    __syncthreads();

    #pragma unroll
    for (int q = 0; q < 4; q++) {
        int p = q * 64 + l;           // 0..255 : (b, jl)
        int b = p >> 3, jl = p & 7, j = j0 + jl;
        float xi = gl[b][jl]      + bias[j];
        float xf = gl[b][8 + jl]  + bias[HD + j];
        float xg = gl[b][16 + jl] + bias[2 * HD + j];
        float xo = gl[b][24 + jl] + bias[3 * HD + j];
        float si = 1.f / (1.f + expf(-xi));
        float sf = 1.f / (1.f + expf(-xf));
        float so = 1.f / (1.f + expf(-xo));
        float tg = tanhf(xg);
        float cn = sf * c_st[b * HD + j] + si * tg;
        float hn = so * tanhf(cn);
        c_st[b * HD + j] = cn;
        short hb = f2bf(hn);
        hout[b * HD + j] = hb;
        Hmat[((long)b * TD + t) * HD + j] = hb;
    }
}

// ---------------- big GEMM: [2048,1024] x [32000,1024]^T -> logits ----------------
__global__ __launch_bounds__(256) void gemm_logits(
    const short* __restrict__ A,    // Hmat [2048][1024] bf16
    const short* __restrict__ Bw,   // W_out [32000][1024] bf16
    const float* __restrict__ bout, // [32000]
    float* __restrict__ C)          // [2048][32000]
{
    __shared__ short Al[4096];      // [kc=4][m=128] units of 8 bf16 (16B)
    __shared__ short Bl[4096];
    const int tid = threadIdx.x;
    const int lane = tid & 63, wv = tid >> 6;
    const int lo = lane & 15, hi = lane >> 4;
    const int wm = wv >> 1, wn = wv & 1;
    const int bm = blockIdx.y, bn = blockIdx.x;
    const long arow0 = (long)bm * 128;
    const long brow0 = (long)bn * 128;

    const int u0 = tid, u1 = tid + 256;
    const int kc0 = u0 >> 7, m0 = u0 & 127;
    const int kc1 = u1 >> 7, m1 = u1 & 127;
    const short* gA0 = A  + (arow0 + m0) * HD + kc0 * 8;
    const short* gA1 = A  + (arow0 + m1) * HD + kc1 * 8;
    const short* gB0 = Bw + (brow0 + m0) * HD + kc0 * 8;
    const short* gB1 = Bw + (brow0 + m1) * HD + kc1 * 8;

    f32x4 acc[4][4] = {};
    for (int ks = 0; ks < 32; ks++) {
        const int k0 = ks * 32;
        __builtin_amdgcn_global_load_lds((const __attribute__((address_space(1))) short*)(gA0 + k0),
                                         (__attribute__((address_space(3))) short*)&Al[u0 * 8], 16, 0, 0);
        __builtin_amdgcn_global_load_lds((const __attribute__((address_space(1))) short*)(gA1 + k0),
                                         (__attribute__((address_space(3))) short*)&Al[u1 * 8], 16, 0, 0);
        __builtin_amdgcn_global_load_lds((const __attribute__((address_space(1))) short*)(gB0 + k0),
                                         (__attribute__((address_space(3))) short*)&Bl[u0 * 8], 16, 0, 0);
        __builtin_amdgcn_global_load_lds((const __attribute__((address_space(1))) short*)(gB1 + k0),
                                         (__attribute__((address_space(3))) short*)&Bl[u1 * 8], 16, 0, 0);
        asm volatile("s_waitcnt vmcnt(0)" ::: "memory");
        __syncthreads();

        bf16x8 af[4], bfr[4];
        #pragma unroll
        for (int mf = 0; mf < 4; mf++)
            af[mf] = *(const bf16x8*)&Al[(hi * 128 + wm * 64 + mf * 16 + lo) * 8];
        #pragma unroll
        for (int nf = 0; nf < 4; nf++)
            bfr[nf] = *(const bf16x8*)&Bl[(hi * 128 + wn * 64 + nf * 16 + lo) * 8];
        #pragma unroll
        for (int mf = 0; mf < 4; mf++)
            #pragma unroll
            for (int nf = 0; nf < 4; nf++)
                acc[mf][nf] = __builtin_amdgcn_mfma_f32_16x16x32_bf16(af[mf], bfr[nf], acc[mf][nf], 0, 0, 0);
        __syncthreads();
    }

    float bo[4];
    #pragma unroll
    for (int nf = 0; nf < 4; nf++) bo[nf] = bout[brow0 + wn * 64 + nf * 16 + lo];
    #pragma unroll
    for (int mf = 0; mf < 4; mf++)
        #pragma unroll
        for (int r = 0; r < 4; r++) {
            long row = arow0 + wm * 64 + mf * 16 + hi * 4 + r;
            float* cp = C + row * VD + brow0 + wn * 64 + lo;
            #pragma unroll
            for (int nf = 0; nf < 4; nf++)
                cp[nf * 16] = acc[mf][nf][r] + bo[nf];
        }
}

// ---------------- in-place log_softmax over rows of [2048, 32000] ----------------
__global__ __launch_bounds__(256) void logsoftmax_inplace(float* __restrict__ C)
{
    const long row = blockIdx.x;
    float* p = C + row * (long)VD;
    const int tid = threadIdx.x;
    float m = -3.4e38f, s = 0.f;
    for (int i = tid; i < VD / 4; i += 256) {
        float4 x = ((const float4*)p)[i];
        float mx = fmaxf(fmaxf(x.x, x.y), fmaxf(x.z, x.w));
        if (mx > m) { s *= __expf(m - mx); m = mx; }
        s += __expf(x.x - m) + __expf(x.y - m) + __expf(x.z - m) + __expf(x.w - m);
    }
    #pragma unroll
    for (int off = 32; off > 0; off >>= 1) {
        float m2 = __shfl_xor(m, off, 64);
        float s2 = __shfl_xor(s, off, 64);
        float mn = fmaxf(m, m2);
        s = s * __expf(m - mn) + s2 * __expf(m2 - mn);
        m = mn;
    }
    __shared__ float sm[4], ss[4];
    if ((tid & 63) == 0) { sm[tid >> 6] = m; ss[tid >> 6] = s; }
    __syncthreads();
    float M = fmaxf(fmaxf(sm[0], sm[1]), fmaxf(sm[2], sm[3]));
    float S = ss[0] * __expf(sm[0] - M) + ss[1] * __expf(sm[1] - M) +
              ss[2] * __expf(sm[2] - M) + ss[3] * __expf(sm[3] - M);
    float lse = M + logf(S);
    for (int i = tid; i < VD / 4; i += 256) {
        float4 x = ((float4*)p)[i];
        x.x -= lse; x.y -= lse; x.z -= lse; x.w -= lse;
        ((float4*)p)[i] = x;
    }
}

extern "C" void kernel_launch(void* const* d_in, const int* in_sizes, int n_in,
                              void* d_out, int out_size, void* d_ws, size_t ws_size,
                              hipStream_t stream)
{
    const float* h0   = (const float*)d_in[0];
    const float* c0   = (const float*)d_in[1];
    // d_in[2] = W_ih: decoder input is zeros, contributes only via b_ih.
    const float* Whh  = (const float*)d_in[3];
    const float* bih  = (const float*)d_in[4];
    const float* bhh  = (const float*)d_in[5];
    const float* Wout = (const float*)d_in[6];
    const float* bout = (const float*)d_in[7];

    char* ws = (char*)d_ws;
    short* Wout_b = (short*)ws;  ws += (size_t)VD * HD * 2;        // 65,536,000 B
    short* Whh_b  = (short*)ws;  ws += (size_t)4 * HD * HD * 2;    //  8,388,608 B
    short* Hmat   = (short*)ws;  ws += (size_t)BD * TD * HD * 2;   //  4,194,304 B
    short* h_st   = (short*)ws;  ws += (size_t)2 * BD * HD * 2;    //    131,072 B (ping-pong)
    float* c_st   = (float*)ws;  ws += (size_t)BD * HD * 4;        //    131,072 B
    float* bias   = (float*)ws;  ws += (size_t)4 * HD * 4;         //     16,384 B
    float* C      = (float*)d_out;

    init_kernel<<<2048, 256, 0, stream>>>(Whh, bih, bhh, Wout, h0, c0,
                                          Whh_b, Wout_b, bias, h_st, c_st);
    for (int t = 0; t < TD; t++) {
        const short* hin = h_st + (size_t)(t & 1) * BD * HD;
        short* hout      = h_st + (size_t)((t + 1) & 1) * BD * HD;
        lstm_step<<<128, 64, 0, stream>>>(Whh_b, bias, hin, hout, c_st, Hmat, t);
    }
    gemm_logits<<<dim3(250, 16), 256, 0, stream>>>(Hmat, Wout_b, bout, C);
    logsoftmax_inplace<<<2048, 256, 0, stream>>>(C);
}

// Round 2
// 804.675 us; speedup vs baseline: 1.5198x; 1.5198x over previous
//
#include <hip/hip_runtime.h>
#include <hip/hip_bf16.h>
#include <math.h>

#define HD 1024
#define BD 32
#define TD 64
#define VD 32000

typedef __attribute__((ext_vector_type(8))) short bf16x8;
typedef __attribute__((ext_vector_type(4))) float f32x4;

__device__ __forceinline__ short f2bf(float x) {
    __hip_bfloat16 h = __float2bfloat16(x);
    union { __hip_bfloat16 h; short s; } u; u.h = h; return u.s;
}
__device__ __forceinline__ float fsigmoid(float x) {
    return 1.f / (1.f + __expf(-x));
}
__device__ __forceinline__ float ftanh(float x) {
    // tanh(x) = 1 - 2/(exp(2x)+1); exp overflow -> inf -> 1, underflow -> -1
    return 1.f - 2.f / (__expf(2.f * x) + 1.f);
}

// ---------------- init: casts + bias fold + state init ----------------
__global__ __launch_bounds__(256) void init_kernel(
    const float* __restrict__ Whh_f, const float* __restrict__ bih,
    const float* __restrict__ bhh,  const float* __restrict__ Wout_f,
    const float* __restrict__ h0,   const float* __restrict__ c0,
    short* __restrict__ Whh_b, short* __restrict__ Wout_b,
    float* __restrict__ bias,  short* __restrict__ h_st, float* __restrict__ c_st)
{
    long i0 = (long)blockIdx.x * blockDim.x + threadIdx.x;
    long stride = (long)gridDim.x * blockDim.x;
    for (long i = i0; i < (long)VD * HD / 4; i += stride) {
        float4 x = ((const float4*)Wout_f)[i];
        short4 y; y.x = f2bf(x.x); y.y = f2bf(x.y); y.z = f2bf(x.z); y.w = f2bf(x.w);
        ((short4*)Wout_b)[i] = y;
    }
    for (long i = i0; i < (long)4 * HD * HD / 4; i += stride) {
        float4 x = ((const float4*)Whh_f)[i];
        short4 y; y.x = f2bf(x.x); y.y = f2bf(x.y); y.z = f2bf(x.z); y.w = f2bf(x.w);
        ((short4*)Whh_b)[i] = y;
    }
    for (long i = i0; i < 4 * HD; i += stride) bias[i] = bih[i] + bhh[i];
    for (long i = i0; i < BD * HD; i += stride) {
        h_st[i] = f2bf(h0[i]);   // ping buffer 0
        c_st[i] = c0[i];
    }
}

// ---------------- one LSTM step: 256 WGs x 4 waves, K-split MFMA ----------------
// WG (w,half): hidden indices j in [w*8, w*8+8), batch rows [half*16, half*16+16).
// Wave v computes K-range [v*256, v*256+256); partials reduced via LDS.
__global__ __launch_bounds__(256) void lstm_step(
    const short* __restrict__ Whh_b,   // [4096][1024] bf16
    const float* __restrict__ bias,    // [4096] = b_ih + b_hh
    const short* __restrict__ hin,     // [32][1024] bf16
    short* __restrict__ hout,          // [32][1024] bf16
    float* __restrict__ c_st,          // [32][1024] f32
    short* __restrict__ Hmat,          // [32][64][1024] bf16
    int t)
{
    const int w = blockIdx.x >> 1;       // 0..127  -> j block
    const int half = blockIdx.x & 1;     // 0..1    -> batch half
    const int tid = threadIdx.x;
    const int v = tid >> 6;              // wave 0..3 -> K quarter
    const int l = tid & 63;
    const int lo = l & 15, hi = l >> 4;
    const int j0 = w * 8;
    const int kbase = v * 256;

    // B columns: n = nf*16+lo -> gate g = n>>3, jl = n&7 -> W_hh row g*1024 + j0 + jl
    const short* wB0 = Whh_b + (long)(((lo) >> 3) * HD + j0 + (lo & 7)) * HD;
    const short* wB1 = Whh_b + (long)((((16 + lo)) >> 3) * HD + j0 + ((16 + lo) & 7)) * HD;
    const short* hA  = hin + (half * 16 + lo) * HD;

    f32x4 acc0 = {}, acc1 = {};
    #pragma unroll
    for (int ks = 0; ks < 8; ks++) {
        int k = kbase + ks * 32 + hi * 8;
        bf16x8 a  = *(const bf16x8*)(hA  + k);
        bf16x8 b0 = *(const bf16x8*)(wB0 + k);
        bf16x8 b1 = *(const bf16x8*)(wB1 + k);
        acc0 = __builtin_amdgcn_mfma_f32_16x16x32_bf16(a, b0, acc0, 0, 0, 0);
        acc1 = __builtin_amdgcn_mfma_f32_16x16x32_bf16(a, b1, acc1, 0, 0, 0);
    }

    __shared__ float gl[4][16][33];     // [wave][row][col]
    #pragma unroll
    for (int r = 0; r < 4; r++) {
        gl[v][hi * 4 + r][lo]      = acc0[r];
        gl[v][hi * 4 + r][16 + lo] = acc1[r];
    }
    __syncthreads();

    if (tid < 128) {
        int bl = tid >> 3, jl = tid & 7;     // row-local, j-local
        int b = half * 16 + bl, j = j0 + jl;
        float xi = gl[0][bl][jl]      + gl[1][bl][jl]      + gl[2][bl][jl]      + gl[3][bl][jl]      + bias[j];
        float xf = gl[0][bl][8 + jl]  + gl[1][bl][8 + jl]  + gl[2][bl][8 + jl]  + gl[3][bl][8 + jl]  + bias[HD + j];
        float xg = gl[0][bl][16 + jl] + gl[1][bl][16 + jl] + gl[2][bl][16 + jl] + gl[3][bl][16 + jl] + bias[2 * HD + j];
        float xo = gl[0][bl][24 + jl] + gl[1][bl][24 + jl] + gl[2][bl][24 + jl] + gl[3][bl][24 + jl] + bias[3 * HD + j];
        float cn = fsigmoid(xf) * c_st[b * HD + j] + fsigmoid(xi) * ftanh(xg);
        float hn = fsigmoid(xo) * ftanh(cn);
        c_st[b * HD + j] = cn;
        short hb = f2bf(hn);
        hout[b * HD + j] = hb;
        Hmat[((long)b * TD + t) * HD + j] = hb;
    }
}

// ---------------- big GEMM: [2048,1024] x [32000,1024]^T -> logits ----------------
// 256x256 tile, 8 waves, grid (bm=8, bn=125): co-dispatched WGs share B tile.
__global__ __launch_bounds__(512) void gemm_logits(
    const short* __restrict__ A,    // Hmat [2048][1024] bf16
    const short* __restrict__ Bw,   // W_out [32000][1024] bf16
    const float* __restrict__ bout, // [32000]
    float* __restrict__ C)          // [2048][32000]
{
    __shared__ short Al[8192];      // [kc=4][m=256] units of 8 bf16 (16B)
    __shared__ short Bl[8192];
    const int tid = threadIdx.x;
    const int lane = tid & 63, wv = tid >> 6;
    const int lo = lane & 15, hi = lane >> 4;
    const int wm = wv >> 1, wn = wv & 1;        // 4 M-waves x 2 N-waves
    const int bm = blockIdx.x, bn = blockIdx.y;
    const long arow0 = (long)bm * 256;
    const long brow0 = (long)bn * 256;

    const int u0 = tid, u1 = tid + 512;
    const int kc0 = u0 >> 8, m0 = u0 & 255;
    const int kc1 = u1 >> 8, m1 = u1 & 255;
    const short* gA0 = A  + (arow0 + m0) * HD + kc0 * 8;
    const short* gA1 = A  + (arow0 + m1) * HD + kc1 * 8;
    const short* gB0 = Bw + (brow0 + m0) * HD + kc0 * 8;
    const short* gB1 = Bw + (brow0 + m1) * HD + kc1 * 8;

    f32x4 acc[4][8] = {};
    for (int ks = 0; ks < 32; ks++) {
        const int k0 = ks * 32;
        __builtin_amdgcn_global_load_lds((const __attribute__((address_space(1))) short*)(gA0 + k0),
                                         (__attribute__((address_space(3))) short*)&Al[u0 * 8], 16, 0, 0);
        __builtin_amdgcn_global_load_lds((const __attribute__((address_space(1))) short*)(gA1 + k0),
                                         (__attribute__((address_space(3))) short*)&Al[u1 * 8], 16, 0, 0);
        __builtin_amdgcn_global_load_lds((const __attribute__((address_space(1))) short*)(gB0 + k0),
                                         (__attribute__((address_space(3))) short*)&Bl[u0 * 8], 16, 0, 0);
        __builtin_amdgcn_global_load_lds((const __attribute__((address_space(1))) short*)(gB1 + k0),
                                         (__attribute__((address_space(3))) short*)&Bl[u1 * 8], 16, 0, 0);
        asm volatile("s_waitcnt vmcnt(0)" ::: "memory");
        __syncthreads();

        bf16x8 af[4], bfr[8];
        #pragma unroll
        for (int mf = 0; mf < 4; mf++)
            af[mf] = *(const bf16x8*)&Al[(hi * 256 + wm * 64 + mf * 16 + lo) * 8];
        #pragma unroll
        for (int nf = 0; nf < 8; nf++)
            bfr[nf] = *(const bf16x8*)&Bl[(hi * 256 + wn * 128 + nf * 16 + lo) * 8];
        #pragma unroll
        for (int mf = 0; mf < 4; mf++)
            #pragma unroll
            for (int nf = 0; nf < 8; nf++)
                acc[mf][nf] = __builtin_amdgcn_mfma_f32_16x16x32_bf16(af[mf], bfr[nf], acc[mf][nf], 0, 0, 0);
        __syncthreads();
    }

    float bo[8];
    #pragma unroll
    for (int nf = 0; nf < 8; nf++) bo[nf] = bout[brow0 + wn * 128 + nf * 16 + lo];
    #pragma unroll
    for (int mf = 0; mf < 4; mf++)
        #pragma unroll
        for (int r = 0; r < 4; r++) {
            long row = arow0 + wm * 64 + mf * 16 + hi * 4 + r;
            float* cp = C + row * VD + brow0 + wn * 128 + lo;
            #pragma unroll
            for (int nf = 0; nf < 8; nf++)
                cp[nf * 16] = acc[mf][nf][r] + bo[nf];
        }
}

// ---------------- in-place log_softmax over rows of [2048, 32000] ----------------
__global__ __launch_bounds__(256) void logsoftmax_inplace(float* __restrict__ C)
{
    const long row = blockIdx.x;
    float* p = C + row * (long)VD;
    const int tid = threadIdx.x;
    float m = -3.4e38f, s = 0.f;
    for (int i = tid; i < VD / 4; i += 256) {
        float4 x = ((const float4*)p)[i];
        float mx = fmaxf(fmaxf(x.x, x.y), fmaxf(x.z, x.w));
        if (mx > m) { s *= __expf(m - mx); m = mx; }
        s += __expf(x.x - m) + __expf(x.y - m) + __expf(x.z - m) + __expf(x.w - m);
    }
    #pragma unroll
    for (int off = 32; off > 0; off >>= 1) {
        float m2 = __shfl_xor(m, off, 64);
        float s2 = __shfl_xor(s, off, 64);
        float mn = fmaxf(m, m2);
        s = s * __expf(m - mn) + s2 * __expf(m2 - mn);
        m = mn;
    }
    __shared__ float sm[4], ss[4];
    if ((tid & 63) == 0) { sm[tid >> 6] = m; ss[tid >> 6] = s; }
    __syncthreads();
    float M = fmaxf(fmaxf(sm[0], sm[1]), fmaxf(sm[2], sm[3]));
    float S = ss[0] * __expf(sm[0] - M) + ss[1] * __expf(sm[1] - M) +
              ss[2] * __expf(sm[2] - M) + ss[3] * __expf(sm[3] - M);
    float lse = M + logf(S);
    for (int i = tid; i < VD / 4; i += 256) {
        float4 x = ((float4*)p)[i];
        x.x -= lse; x.y -= lse; x.z -= lse; x.w -= lse;
        ((float4*)p)[i] = x;
    }
}

extern "C" void kernel_launch(void* const* d_in, const int* in_sizes, int n_in,
                              void* d_out, int out_size, void* d_ws, size_t ws_size,
                              hipStream_t stream)
{
    const float* h0   = (const float*)d_in[0];
    const float* c0   = (const float*)d_in[1];
    // d_in[2] = W_ih: decoder input is zeros, contributes only via b_ih.
    const float* Whh  = (const float*)d_in[3];
    const float* bih  = (const float*)d_in[4];
    const float* bhh  = (const float*)d_in[5];
    const float* Wout = (const float*)d_in[6];
    const float* bout = (const float*)d_in[7];

    char* ws = (char*)d_ws;
    short* Wout_b = (short*)ws;  ws += (size_t)VD * HD * 2;        // 65,536,000 B
    short* Whh_b  = (short*)ws;  ws += (size_t)4 * HD * HD * 2;    //  8,388,608 B
    short* Hmat   = (short*)ws;  ws += (size_t)BD * TD * HD * 2;   //  4,194,304 B
    short* h_st   = (short*)ws;  ws += (size_t)2 * BD * HD * 2;    //    131,072 B (ping-pong)
    float* c_st   = (float*)ws;  ws += (size_t)BD * HD * 4;        //    131,072 B
    float* bias   = (float*)ws;  ws += (size_t)4 * HD * 4;         //     16,384 B
    float* C      = (float*)d_out;

    init_kernel<<<2048, 256, 0, stream>>>(Whh, bih, bhh, Wout, h0, c0,
                                          Whh_b, Wout_b, bias, h_st, c_st);
    for (int t = 0; t < TD; t++) {
        const short* hin = h_st + (size_t)(t & 1) * BD * HD;
        short* hout      = h_st + (size_t)((t + 1) & 1) * BD * HD;
        lstm_step<<<256, 256, 0, stream>>>(Whh_b, bias, hin, hout, c_st, Hmat, t);
    }
    gemm_logits<<<dim3(8, 125), 512, 0, stream>>>(Hmat, Wout_b, bout, C);
    logsoftmax_inplace<<<2048, 256, 0, stream>>>(C);
}

// Round 3
// 758.706 us; speedup vs baseline: 1.6119x; 1.0606x over previous
//
#include <hip/hip_runtime.h>
#include <hip/hip_bf16.h>
#include <math.h>

#define HD 1024
#define BD 32
#define TD 64
#define VD 32000

typedef __attribute__((ext_vector_type(8))) short bf16x8;
typedef __attribute__((ext_vector_type(4))) float f32x4;

__device__ __forceinline__ short f2bf(float x) {
    __hip_bfloat16 h = __float2bfloat16(x);
    union { __hip_bfloat16 h; short s; } u; u.h = h; return u.s;
}
__device__ __forceinline__ float fsigmoid(float x) {
    return 1.f / (1.f + __expf(-x));
}
__device__ __forceinline__ float ftanh(float x) {
    return 1.f - 2.f / (__expf(2.f * x) + 1.f);
}

// ---------------- init: casts + bias fold + state init ----------------
__global__ __launch_bounds__(256) void init_kernel(
    const float* __restrict__ Whh_f, const float* __restrict__ bih,
    const float* __restrict__ bhh,  const float* __restrict__ Wout_f,
    const float* __restrict__ h0,   const float* __restrict__ c0,
    short* __restrict__ Whh_b, short* __restrict__ Wout_b,
    float* __restrict__ bias,  short* __restrict__ h_st, float* __restrict__ c_st)
{
    long i0 = (long)blockIdx.x * blockDim.x + threadIdx.x;
    long stride = (long)gridDim.x * blockDim.x;
    for (long i = i0; i < (long)VD * HD / 4; i += stride) {
        float4 x = ((const float4*)Wout_f)[i];
        short4 y; y.x = f2bf(x.x); y.y = f2bf(x.y); y.z = f2bf(x.z); y.w = f2bf(x.w);
        ((short4*)Wout_b)[i] = y;
    }
    for (long i = i0; i < (long)4 * HD * HD / 4; i += stride) {
        float4 x = ((const float4*)Whh_f)[i];
        short4 y; y.x = f2bf(x.x); y.y = f2bf(x.y); y.z = f2bf(x.z); y.w = f2bf(x.w);
        ((short4*)Whh_b)[i] = y;
    }
    for (long i = i0; i < 4 * HD; i += stride) bias[i] = bih[i] + bhh[i];
    for (long i = i0; i < BD * HD; i += stride) {
        h_st[i] = f2bf(h0[i]);
        c_st[i] = c0[i];
    }
}

// ---------------- one LSTM step: 128 WGs x 4 waves, full batch, K-split ----------------
// WG w: hidden indices j in [w*8, w*8+8), all 32 batch rows, all 4 gates.
// Wave v computes K-range [v*256, v*256+256); partials reduced via LDS.
__global__ __launch_bounds__(256) void lstm_step(
    const short* __restrict__ Whh_b,   // [4096][1024] bf16
    const float* __restrict__ bias,    // [4096] = b_ih + b_hh
    const short* __restrict__ hin,     // [32][1024] bf16
    short* __restrict__ hout,          // [32][1024] bf16
    float* __restrict__ c_st,          // [32][1024] f32
    short* __restrict__ Hmat,          // [32][64][1024] bf16
    int t)
{
    const int w = blockIdx.x;            // 0..127 -> j block
    const int tid = threadIdx.x;
    const int v = tid >> 6;              // wave 0..3 -> K quarter
    const int l = tid & 63;
    const int lo = l & 15, hi = l >> 4;
    const int j0 = w * 8;
    const int kbase = v * 256;

    // B cols: n = nf*16+lo -> gate g=n>>3, jl=n&7 -> W_hh row g*1024 + j0 + jl
    const short* wB0 = Whh_b + (long)((lo >> 3) * HD + j0 + (lo & 7)) * HD;
    const short* wB1 = Whh_b + (long)(((16 + lo) >> 3) * HD + j0 + ((16 + lo) & 7)) * HD;
    const short* hA0 = hin + lo * HD;
    const short* hA1 = hin + (16 + lo) * HD;

    f32x4 acc[2][2] = {};
    #pragma unroll
    for (int ks = 0; ks < 8; ks++) {
        int k = kbase + ks * 32 + hi * 8;
        bf16x8 a0 = *(const bf16x8*)(hA0 + k);
        bf16x8 a1 = *(const bf16x8*)(hA1 + k);
        bf16x8 b0 = *(const bf16x8*)(wB0 + k);
        bf16x8 b1 = *(const bf16x8*)(wB1 + k);
        acc[0][0] = __builtin_amdgcn_mfma_f32_16x16x32_bf16(a0, b0, acc[0][0], 0, 0, 0);
        acc[0][1] = __builtin_amdgcn_mfma_f32_16x16x32_bf16(a0, b1, acc[0][1], 0, 0, 0);
        acc[1][0] = __builtin_amdgcn_mfma_f32_16x16x32_bf16(a1, b0, acc[1][0], 0, 0, 0);
        acc[1][1] = __builtin_amdgcn_mfma_f32_16x16x32_bf16(a1, b1, acc[1][1], 0, 0, 0);
    }

    __shared__ float gl[4][32][33];      // [wave][batch][gatecol]
    #pragma unroll
    for (int mf = 0; mf < 2; mf++)
        #pragma unroll
        for (int nf = 0; nf < 2; nf++)
            #pragma unroll
            for (int r = 0; r < 4; r++)
                gl[v][mf * 16 + hi * 4 + r][nf * 16 + lo] = acc[mf][nf][r];
    __syncthreads();

    {
        int b = tid >> 3, jl = tid & 7, j = j0 + jl;   // 256 threads = 32 b x 8 jl
        float xi = gl[0][b][jl]      + gl[1][b][jl]      + gl[2][b][jl]      + gl[3][b][jl]      + bias[j];
        float xf = gl[0][b][8 + jl]  + gl[1][b][8 + jl]  + gl[2][b][8 + jl]  + gl[3][b][8 + jl]  + bias[HD + j];
        float xg = gl[0][b][16 + jl] + gl[1][b][16 + jl] + gl[2][b][16 + jl] + gl[3][b][16 + jl] + bias[2 * HD + j];
        float xo = gl[0][b][24 + jl] + gl[1][b][24 + jl] + gl[2][b][24 + jl] + gl[3][b][24 + jl] + bias[3 * HD + j];
        float cn = fsigmoid(xf) * c_st[b * HD + j] + fsigmoid(xi) * ftanh(xg);
        float hn = fsigmoid(xo) * ftanh(cn);
        c_st[b * HD + j] = cn;
        short hb = f2bf(hn);
        hout[b * HD + j] = hb;
        Hmat[((long)b * TD + t) * HD + j] = hb;
    }
}

// ---------------- big GEMM: [2048,1024] x [32000,1024]^T -> logits ----------------
// 256x256 tile, BK=32, 3-buffer LDS ring, counted vmcnt(4), XOR-swizzled LDS.
// 8 waves: wm = wv>>2 (2), wn = wv&3 (4); per-wave output 128x64 (acc[8][4]).
__global__ __launch_bounds__(512, 2) void gemm_logits(
    const short* __restrict__ A,    // Hmat [2048][1024] bf16
    const short* __restrict__ Bw,   // W_out [32000][1024] bf16
    const float* __restrict__ bout, // [32000]
    float* __restrict__ C)          // [2048][32000]
{
    // 3 buffers x (A:1024 + B:1024 units of 16B) = 96 KiB
    __shared__ short lds[3 * 2048 * 8];
    const int tid = threadIdx.x;
    const int lane = tid & 63, wv = tid >> 6;
    const int lo = lane & 15, hi = lane >> 4;
    const int wm = wv >> 2, wn = wv & 3;
    const long arow0 = (long)blockIdx.x * 256;   // bm fastest -> B shared across XCD round
    const long brow0 = (long)blockIdx.y * 256;

    // staging: thread covers phys units u0,u1 for A and for B.
    // phys unit u -> row = u>>2, phys kc = u&3, logical kc = pkc ^ swz(row)
    const int u0 = tid, u1 = tid + 512;
    const int pr0 = u0 >> 2, pr1 = u1 >> 2;
    const int lkc0 = (u0 & 3) ^ ((pr0 + (pr0 >> 2)) & 3);
    const int lkc1 = (u1 & 3) ^ ((pr1 + (pr1 >> 2)) & 3);
    const short* sA0 = A  + (arow0 + pr0) * HD + lkc0 * 8;
    const short* sA1 = A  + (arow0 + pr1) * HD + lkc1 * 8;
    const short* sB0 = Bw + (brow0 + pr0) * HD + lkc0 * 8;
    const short* sB1 = Bw + (brow0 + pr1) * HD + lkc1 * 8;

#define STAGE(koff, bb) do { \
    __builtin_amdgcn_global_load_lds((const __attribute__((address_space(1))) short*)(sA0 + (koff)), \
        (__attribute__((address_space(3))) short*)&lds[((bb) + u0) * 8], 16, 0, 0); \
    __builtin_amdgcn_global_load_lds((const __attribute__((address_space(1))) short*)(sA1 + (koff)), \
        (__attribute__((address_space(3))) short*)&lds[((bb) + u1) * 8], 16, 0, 0); \
    __builtin_amdgcn_global_load_lds((const __attribute__((address_space(1))) short*)(sB0 + (koff)), \
        (__attribute__((address_space(3))) short*)&lds[((bb) + 1024 + u0) * 8], 16, 0, 0); \
    __builtin_amdgcn_global_load_lds((const __attribute__((address_space(1))) short*)(sB1 + (koff)), \
        (__attribute__((address_space(3))) short*)&lds[((bb) + 1024 + u1) * 8], 16, 0, 0); \
} while (0)

    // read-side swizzled unit offsets (lane-constant across tiles)
    int unitA[8], unitB[4];
    #pragma unroll
    for (int mf = 0; mf < 8; mf++) {
        int row = wm * 128 + mf * 16 + lo;
        unitA[mf] = row * 4 + (hi ^ ((row + (row >> 2)) & 3));
    }
    #pragma unroll
    for (int nf = 0; nf < 4; nf++) {
        int row = wn * 64 + nf * 16 + lo;
        unitB[nf] = 1024 + row * 4 + (hi ^ ((row + (row >> 2)) & 3));
    }

    f32x4 acc[8][4] = {};

    // prologue: tile0 -> buf0, tile1 -> buf1; wait tile0 (4 of 8 outstanding ok)
    STAGE(0, 0);
    STAGE(32, 2048);
    asm volatile("s_waitcnt vmcnt(4)\n\ts_barrier" ::: "memory");

    int br = 0;  // read buffer
    for (int kt = 0; kt < 32; ++kt) {
        int bs = br + 2; if (bs >= 3) bs -= 3;           // stage buffer (last read kt-1)
        int koff = (kt + 2 < 32 ? kt + 2 : 31) * 32;     // clamp: dummy re-stage at tail
        STAGE(koff, bs * 2048);

        const int bb = br * 2048;
#define LDF(u) (*(const bf16x8*)&lds[((bb) + (u)) * 8])
        bf16x8 a[8], b[4];
        #pragma unroll
        for (int mf = 0; mf < 4; mf++) a[mf] = LDF(unitA[mf]);
        b[0] = LDF(unitB[0]); b[1] = LDF(unitB[1]);
        __builtin_amdgcn_s_setprio(1);
        #pragma unroll
        for (int mf = 0; mf < 4; mf++) {
            acc[mf][0] = __builtin_amdgcn_mfma_f32_16x16x32_bf16(a[mf], b[0], acc[mf][0], 0, 0, 0);
            acc[mf][1] = __builtin_amdgcn_mfma_f32_16x16x32_bf16(a[mf], b[1], acc[mf][1], 0, 0, 0);
        }
        __builtin_amdgcn_s_setprio(0);
        b[2] = LDF(unitB[2]); b[3] = LDF(unitB[3]);
        __builtin_amdgcn_s_setprio(1);
        #pragma unroll
        for (int mf = 0; mf < 4; mf++) {
            acc[mf][2] = __builtin_amdgcn_mfma_f32_16x16x32_bf16(a[mf], b[2], acc[mf][2], 0, 0, 0);
            acc[mf][3] = __builtin_amdgcn_mfma_f32_16x16x32_bf16(a[mf], b[3], acc[mf][3], 0, 0, 0);
        }
        __builtin_amdgcn_s_setprio(0);
        #pragma unroll
        for (int mf = 4; mf < 8; mf++) a[mf] = LDF(unitA[mf]);
        __builtin_amdgcn_s_setprio(1);
        #pragma unroll
        for (int mf = 4; mf < 8; mf++) {
            acc[mf][2] = __builtin_amdgcn_mfma_f32_16x16x32_bf16(a[mf], b[2], acc[mf][2], 0, 0, 0);
            acc[mf][3] = __builtin_amdgcn_mfma_f32_16x16x32_bf16(a[mf], b[3], acc[mf][3], 0, 0, 0);
        }
        __builtin_amdgcn_s_setprio(0);
        __builtin_amdgcn_s_setprio(1);
        #pragma unroll
        for (int mf = 4; mf < 8; mf++) {
            acc[mf][0] = __builtin_amdgcn_mfma_f32_16x16x32_bf16(a[mf], b[0], acc[mf][0], 0, 0, 0);
            acc[mf][1] = __builtin_amdgcn_mfma_f32_16x16x32_bf16(a[mf], b[1], acc[mf][1], 0, 0, 0);
        }
        __builtin_amdgcn_s_setprio(0);
#undef LDF
        // tile kt+1 (issued during kt-1) must be landed; kt+2's 4 stay in flight
        asm volatile("s_waitcnt vmcnt(4)\n\ts_barrier" ::: "memory");
        br = (br + 1 == 3) ? 0 : br + 1;
    }
#undef STAGE

    float bo[4];
    #pragma unroll
    for (int nf = 0; nf < 4; nf++) bo[nf] = bout[brow0 + wn * 64 + nf * 16 + lo];
    #pragma unroll
    for (int mf = 0; mf < 8; mf++)
        #pragma unroll
        for (int r = 0; r < 4; r++) {
            long row = arow0 + wm * 128 + mf * 16 + hi * 4 + r;
            float* cp = C + row * VD + brow0 + wn * 64 + lo;
            #pragma unroll
            for (int nf = 0; nf < 4; nf++)
                cp[nf * 16] = acc[mf][nf][r] + bo[nf];
        }
}

// ---------------- in-place log_softmax over rows of [2048, 32000] ----------------
__global__ __launch_bounds__(256) void logsoftmax_inplace(float* __restrict__ C)
{
    const long row = blockIdx.x;
    float* p = C + row * (long)VD;
    const int tid = threadIdx.x;
    float m = -3.4e38f, s = 0.f;
    for (int i = tid; i < VD / 4; i += 256) {
        float4 x = ((const float4*)p)[i];
        float mx = fmaxf(fmaxf(x.x, x.y), fmaxf(x.z, x.w));
        if (mx > m) { s *= __expf(m - mx); m = mx; }
        s += __expf(x.x - m) + __expf(x.y - m) + __expf(x.z - m) + __expf(x.w - m);
    }
    #pragma unroll
    for (int off = 32; off > 0; off >>= 1) {
        float m2 = __shfl_xor(m, off, 64);
        float s2 = __shfl_xor(s, off, 64);
        float mn = fmaxf(m, m2);
        s = s * __expf(m - mn) + s2 * __expf(m2 - mn);
        m = mn;
    }
    __shared__ float sm[4], ss[4];
    if ((tid & 63) == 0) { sm[tid >> 6] = m; ss[tid >> 6] = s; }
    __syncthreads();
    float M = fmaxf(fmaxf(sm[0], sm[1]), fmaxf(sm[2], sm[3]));
    float S = ss[0] * __expf(sm[0] - M) + ss[1] * __expf(sm[1] - M) +
              ss[2] * __expf(sm[2] - M) + ss[3] * __expf(sm[3] - M);
    float lse = M + logf(S);
    for (int i = tid; i < VD / 4; i += 256) {
        float4 x = ((float4*)p)[i];
        x.x -= lse; x.y -= lse; x.z -= lse; x.w -= lse;
        ((float4*)p)[i] = x;
    }
}

extern "C" void kernel_launch(void* const* d_in, const int* in_sizes, int n_in,
                              void* d_out, int out_size, void* d_ws, size_t ws_size,
                              hipStream_t stream)
{
    const float* h0   = (const float*)d_in[0];
    const float* c0   = (const float*)d_in[1];
    // d_in[2] = W_ih: decoder input is zeros, contributes only via b_ih.
    const float* Whh  = (const float*)d_in[3];
    const float* bih  = (const float*)d_in[4];
    const float* bhh  = (const float*)d_in[5];
    const float* Wout = (const float*)d_in[6];
    const float* bout = (const float*)d_in[7];

    char* ws = (char*)d_ws;
    short* Wout_b = (short*)ws;  ws += (size_t)VD * HD * 2;
    short* Whh_b  = (short*)ws;  ws += (size_t)4 * HD * HD * 2;
    short* Hmat   = (short*)ws;  ws += (size_t)BD * TD * HD * 2;
    short* h_st   = (short*)ws;  ws += (size_t)2 * BD * HD * 2;
    float* c_st   = (float*)ws;  ws += (size_t)BD * HD * 4;
    float* bias   = (float*)ws;  ws += (size_t)4 * HD * 4;
    float* C      = (float*)d_out;

    init_kernel<<<2048, 256, 0, stream>>>(Whh, bih, bhh, Wout, h0, c0,
                                          Whh_b, Wout_b, bias, h_st, c_st);
    for (int t = 0; t < TD; t++) {
        const short* hin = h_st + (size_t)(t & 1) * BD * HD;
        short* hout      = h_st + (size_t)((t + 1) & 1) * BD * HD;
        lstm_step<<<128, 256, 0, stream>>>(Whh_b, bias, hin, hout, c_st, Hmat, t);
    }
    gemm_logits<<<dim3(8, 125), 512, 0, stream>>>(Hmat, Wout_b, bout, C);
    logsoftmax_inplace<<<2048, 256, 0, stream>>>(C);
}